// Round 4
// baseline (103.902 us; speedup 1.0000x reference)
//
#include <hip/hip_runtime.h>
#include <math.h>

// Exact IEEE semantics in the visibility path: no fma contraction anywhere.
#pragma clang fp contract(off)

#define IMG_H 128
#define IMG_W 128
#define HW (IMG_H * IMG_W)
#define NB 2
#define NV 1300
#define NF 2500
#define EPSF 1e-8f
#define NCHUNK 32
#define CHUNK ((NF + NCHUNK - 1) / NCHUNK) // 79
#define NREG 128                            // 8x16 grid of 16w x 8h px regions
#define NBLK (NREG * NB * NCHUNK)           // 8192

// ws layout (bytes):
//   vn     f32[NB*NV*3]          @ 0       (31200 B)
//   face   f4 [4][NB][NF]        @ 31232   (320000 B)  SoA: E0|E1|FD|BB planes
//   dbuf   u64[NCHUNK][NB][HW]   @ 351488  (8 MB)      per-chunk depth|idx slab
#define OFF_FACE 31232
#define OFF_DBUF 351488

#define DINIT 0x7F800000FFFFFFFFull // depth=+inf, fidx=~0

__device__ __forceinline__ float bcastf(float v, int s) {
    return __int_as_float(__builtin_amdgcn_readlane(__float_as_int(v), s));
}

__global__ __launch_bounds__(256) void k_face(const float* __restrict__ verts,
                                              const int* __restrict__ faces,
                                              float* __restrict__ vn,
                                              float4* __restrict__ face) {
    int i = blockIdx.x * 256 + threadIdx.x;
    if (i >= NB * NF) return;
    int b = i / NF;
    int f = i - b * NF;
    int i0 = faces[f * 3 + 0];
    int i1 = faces[f * 3 + 1];
    int i2 = faces[f * 3 + 2];
    const float* wv = verts + (size_t)b * NV * 3;
    // transform, bit-identical to ref: ndc = (12*(-vx))/(2-vz), z = 2-vz
    float v0x = wv[i0 * 3 + 0], v0y = wv[i0 * 3 + 1], v0z = wv[i0 * 3 + 2];
    float v1x = wv[i1 * 3 + 0], v1y = wv[i1 * 3 + 1], v1z = wv[i1 * 3 + 2];
    float v2x = wv[i2 * 3 + 0], v2y = wv[i2 * 3 + 1], v2z = wv[i2 * 3 + 2];
    float z0 = 2.0f - v0z, z1 = 2.0f - v1z, z2 = 2.0f - v2z;
    float p0x = (12.0f * (-v0x)) / z0, p0y = (12.0f * v0y) / z0;
    float p1x = (12.0f * (-v1x)) / z1, p1y = (12.0f * v1y) / z1;
    float p2x = (12.0f * (-v2x)) / z2, p2y = (12.0f * v2y) / z2;

    float t1 = (p1x - p0x) * (p2y - p0y);
    float t2 = (p1y - p0y) * (p2x - p0x);
    float area = t1 - t2;
    float aabs = fabsf(area);
    float area_safe = (aabs < EPSF) ? EPSF : area;
    bool valid = aabs > EPSF;
    float minx, maxx, miny, maxy;
    if (valid) {
        minx = fminf(p0x, fminf(p1x, p2x)) - 1e-3f;
        maxx = fmaxf(p0x, fmaxf(p1x, p2x)) + 1e-3f;
        miny = fminf(p0y, fminf(p1y, p2y)) - 1e-3f;
        maxy = fmaxf(p0y, fmaxf(p1y, p2y)) + 1e-3f;
    } else {
        minx = 1e30f; maxx = -1e30f; miny = 1e30f; maxy = -1e30f;
    }
    // SoA planes: E0 | E1 | FD | BB, each [NB][NF] float4 -> coalesced reads
    int o = b * NF + f;
    face[0 * NB * NF + o] = make_float4(p2x - p1x, p2y - p1y, p1x, p1y);
    face[1 * NB * NF + o] = make_float4(p0x - p2x, p0y - p2y, p2x, p2y);
    face[2 * NB * NF + o] = make_float4(area_safe, z0, z1, z2);
    face[3 * NB * NF + o] = make_float4(minx, maxx, miny, maxy);

    // world-space face normal -> scatter to vertex normals
    float ax = v1x - v0x, ay = v1y - v0y, az = v1z - v0z;
    float bx = v2x - v0x, by = v2y - v0y, bz = v2z - v0z;
    float fnx = ay * bz - az * by;
    float fny = az * bx - ax * bz;
    float fnz = ax * by - ay * bx;
    float* vnb = vn + (size_t)b * NV * 3;
    atomicAdd(&vnb[i0 * 3 + 0], fnx);
    atomicAdd(&vnb[i0 * 3 + 1], fny);
    atomicAdd(&vnb[i0 * 3 + 2], fnz);
    atomicAdd(&vnb[i1 * 3 + 0], fnx);
    atomicAdd(&vnb[i1 * 3 + 1], fny);
    atomicAdd(&vnb[i1 * 3 + 2], fnz);
    atomicAdd(&vnb[i2 * 3 + 0], fnx);
    atomicAdd(&vnb[i2 * 3 + 1], fny);
    atomicAdd(&vnb[i2 * 3 + 2], fnz);
}

// Block = 128 threads = 2 fully independent waves, ZERO LDS, zero barriers.
// Each wave owns an 8x8 px tile. Per 64-face round: every lane loads one
// face's full record (4 coalesced SoA float4 loads, unconditional), tests
// bbox-vs-tile + conservative edge-corner cull, then the wave walks the
// ballot mask and redistributes survivor data via v_readlane broadcasts,
// running the bit-exact per-pixel path. One coalesced slab store at the end.
__global__ __launch_bounds__(128) void k_raster(const float4* __restrict__ face,
                                                unsigned long long* __restrict__ dbuf) {
    int bx = blockIdx.x;
    int chunk = bx & (NCHUNK - 1);
    int tmp = bx >> 5;
    int b = tmp & 1;
    int reg = tmp >> 1;       // 0..127
    int r0 = (reg >> 3) * 8;  // 16 row-bands of 8 px
    int c0 = (reg & 7) * 16;  // 8 col-bands of 16 px
    int f0 = chunk * CHUNK;
    int nf = NF - f0; if (nf > CHUNK) nf = CHUNK;

    int t = threadIdx.x;
    int wid = t >> 6, lid = t & 63;
    int cw0 = c0 + wid * 8;

    // px(c) = 1 - (2c+1)/128, strictly decreasing in c; tile pixel-center box.
    float txhi = 1.0f - (2.0f * (float)cw0 + 1.0f) / 128.0f;
    float txlo = 1.0f - (2.0f * (float)(cw0 + 7) + 1.0f) / 128.0f;
    float tyhi = 1.0f - (2.0f * (float)r0 + 1.0f) / 128.0f;
    float tylo = 1.0f - (2.0f * (float)(r0 + 7) + 1.0f) / 128.0f;

    const float4* pE0 = face + (size_t)(0 * NB + b) * NF + f0;
    const float4* pE1 = face + (size_t)(1 * NB + b) * NF + f0;
    const float4* pFD = face + (size_t)(2 * NB + b) * NF + f0;
    const float4* pBB = face + (size_t)(3 * NB + b) * NF + f0;

    int r = r0 + (lid >> 3);
    int c = cw0 + (lid & 7);
    int p = r * IMG_W + c;
    float px = 1.0f - (2.0f * (float)c + 1.0f) / 128.0f;
    float py = 1.0f - (2.0f * (float)r + 1.0f) / 128.0f;

    unsigned long long best = DINIT;

    for (int base = 0; base < nf; base += 64) {
        int tt = base + lid;
        int fi = (tt < nf) ? tt : (nf - 1); // clamp: loads stay in-bounds
        float4 bb = pBB[fi]; // {minx, maxx, miny, maxy}
        float4 E0 = pE0[fi];
        float4 E1 = pE1[fi];
        float4 FD = pFD[fi];
        bool pass = false;
        if (tt < nf) {
            pass = (bb.y >= txlo) && (bb.x <= txhi) && (bb.w >= tylo) && (bb.z <= tyhi);
            if (pass) {
                float as = FD.x;
                // Bound each affine edge fn over the tile rect via corner
                // products; all-corners-outside (with DL >> FP rounding of
                // the per-pixel edge expr ~2e-7) => no pixel center passes.
                float u0l = E0.x * (tylo - E0.w), u0h = E0.x * (tyhi - E0.w);
                float u0mn = fminf(u0l, u0h), u0mx = fmaxf(u0l, u0h);
                float u1l = E1.x * (tylo - E1.w), u1h = E1.x * (tyhi - E1.w);
                float u1mn = fminf(u1l, u1h), u1mx = fmaxf(u1l, u1h);
                float v0l = E0.y * (txlo - E0.z), v0h = E0.y * (txhi - E0.z);
                float v0mn = fminf(v0l, v0h), v0mx = fmaxf(v0l, v0h);
                float v1l = E1.y * (txlo - E1.z), v1h = E1.y * (txhi - E1.z);
                float v1mn = fminf(v1l, v1h), v1mx = fmaxf(v1l, v1h);
                float e0mx = u0mx - v0mn, e0mn = u0mn - v0mx;
                float e1mx = u1mx - v1mn, e1mn = u1mn - v1mx;
                const float DL = 1e-4f;
                if (as > 0.0f) {
                    pass = (e0mx >= -DL) && (e1mx >= -DL) && (((as - e0mn) - e1mn) >= -DL);
                } else {
                    pass = (e0mn <= DL) && (e1mn <= DL) && (((as - e0mx) - e1mx) <= DL);
                }
            }
        }
        unsigned long long m = __ballot(pass);
        while (m) {
            int s = (int)__builtin_ctzll(m);
            m &= m - 1;
            // broadcast candidate's bbox from lane s (readlane ignores exec)
            float bmnx = bcastf(bb.x, s), bmxx = bcastf(bb.y, s);
            float bmny = bcastf(bb.z, s), bmxy = bcastf(bb.w, s);
            if (px >= bmnx && px <= bmxx && py >= bmny && py <= bmxy) {
                float e0x = bcastf(E0.x, s), e0y = bcastf(E0.y, s);
                float e0z = bcastf(E0.z, s), e0w = bcastf(E0.w, s);
                float e1x = bcastf(E1.x, s), e1y = bcastf(E1.y, s);
                float e1z = bcastf(E1.z, s), e1w = bcastf(E1.w, s);
                float as  = bcastf(FD.x, s), fz0 = bcastf(FD.y, s);
                float fz1 = bcastf(FD.z, s), fz2 = bcastf(FD.w, s);
                // exact ref order: e = (bx-ax)*(py-ay) - (by-ay)*(px-ax)
                float u1 = e0x * (py - e0w);
                float u2 = e0y * (px - e0z);
                float e0 = u1 - u2;
                float u3 = e1x * (py - e1w);
                float u4 = e1y * (px - e1z);
                float e1 = u3 - u4;
                bool ok = (as > 0.0f) ? (e0 >= 0.0f && e1 >= 0.0f)
                                      : (e0 <= 0.0f && e1 <= 0.0f);
                if (ok) {
                    float b0 = e0 / as; // true IEEE division, as in ref
                    float b1 = e1 / as;
                    float b2 = (1.0f - b0) - b1;
                    if (b2 >= 0.0f) {
                        float S = ((b0 / fz0) + (b1 / fz1)) + (b2 / fz2);
                        if (S > EPSF) {
                            float depth = 1.0f / fmaxf(S, EPSF);
                            unsigned long long pk =
                                ((unsigned long long)__float_as_uint(depth) << 32) |
                                (unsigned)(f0 + base + s);
                            if (pk < best) best = pk;
                        }
                    }
                }
            }
        }
    }
    dbuf[((size_t)chunk * NB + b) * HW + p] = best;
}

__global__ __launch_bounds__(64) void k_shade(const float* __restrict__ verts,
                                              const int* __restrict__ faces,
                                              const float* __restrict__ vn,
                                              const unsigned long long* __restrict__ dbuf,
                                              float* __restrict__ out) {
    int i = blockIdx.x * 64 + threadIdx.x; // 0..NB*HW-1
    int b = i >> 14;
    int p = i & (HW - 1);
    unsigned long long pk = DINIT;
    for (int k = 0; k < NCHUNK; ++k) {
        unsigned long long v = dbuf[((size_t)k * NB + b) * HW + p];
        if (v < pk) pk = v;
    }
    unsigned dbits = (unsigned)(pk >> 32);
    bool hit = dbits < 0x7F800000u;
    float cr = 255.0f, cg = 255.0f, cb = 255.0f, alpha = 0.0f;
    if (hit) {
        alpha = 1.0f;
        int f = (int)(unsigned)(pk & 0xFFFFFFFFull);
        int row = p >> 7;
        int col = p & 127;
        float px = 1.0f - (2.0f * (float)col + 1.0f) / 128.0f;
        float py = 1.0f - (2.0f * (float)row + 1.0f) / 128.0f;
        int i0 = faces[f * 3 + 0];
        int i1 = faces[f * 3 + 1];
        int i2 = faces[f * 3 + 2];
        const float* wv = verts + (size_t)b * NV * 3;
        float v0x = wv[i0 * 3 + 0], v0y = wv[i0 * 3 + 1], v0z = wv[i0 * 3 + 2];
        float v1x = wv[i1 * 3 + 0], v1y = wv[i1 * 3 + 1], v1z = wv[i1 * 3 + 2];
        float v2x = wv[i2 * 3 + 0], v2y = wv[i2 * 3 + 1], v2z = wv[i2 * 3 + 2];
        // transform, bit-identical to k_face/ref
        float z0 = 2.0f - v0z, z1 = 2.0f - v1z, z2 = 2.0f - v2z;
        float a0x = (12.0f * (-v0x)) / z0, a0y = (12.0f * v0y) / z0;
        float a1x = (12.0f * (-v1x)) / z1, a1y = (12.0f * v1y) / z1;
        float a2x = (12.0f * (-v2x)) / z2, a2y = (12.0f * v2y) / z2;

        float t1 = (a1x - a0x) * (a2y - a0y);
        float t2 = (a1y - a0y) * (a2x - a0x);
        float ar = t1 - t2;
        ar = (fabsf(ar) < EPSF) ? EPSF : ar;
        float u1 = (a2x - a1x) * (py - a1y);
        float u2 = (a2y - a1y) * (px - a1x);
        float bb0 = (u1 - u2) / ar;
        float u3 = (a0x - a2x) * (py - a2y);
        float u4 = (a0y - a2y) * (px - a2x);
        float bb1 = (u3 - u4) / ar;
        float bb2 = (1.0f - bb0) - bb1;
        float w0 = bb0 / z0;
        float w1 = bb1 / z1;
        float w2 = bb2 / z2;
        float denom = ((w0 + w1) + w2) + EPSF;
        float pc0 = w0 / denom;
        float pc1 = w1 / denom;
        float pc2 = w2 / denom;

        float posx = (pc0 * v0x + pc1 * v1x) + pc2 * v2x;
        float posy = (pc0 * v0y + pc1 * v1y) + pc2 * v2y;
        float posz = (pc0 * v0z + pc1 * v1z) + pc2 * v2z;

        const float* vnb = vn + (size_t)b * NV * 3;
        float n0x = vnb[i0 * 3 + 0], n0y = vnb[i0 * 3 + 1], n0z = vnb[i0 * 3 + 2];
        float n1x = vnb[i1 * 3 + 0], n1y = vnb[i1 * 3 + 1], n1z = vnb[i1 * 3 + 2];
        float n2x = vnb[i2 * 3 + 0], n2y = vnb[i2 * 3 + 1], n2z = vnb[i2 * 3 + 2];
        float in0 = 1.0f / (sqrtf(n0x * n0x + n0y * n0y + n0z * n0z) + EPSF);
        float in1 = 1.0f / (sqrtf(n1x * n1x + n1y * n1y + n1z * n1z) + EPSF);
        float in2 = 1.0f / (sqrtf(n2x * n2x + n2y * n2y + n2z * n2z) + EPSF);
        n0x *= in0; n0y *= in0; n0z *= in0;
        n1x *= in1; n1y *= in1; n1z *= in1;
        n2x *= in2; n2y *= in2; n2z *= in2;
        float nx = (pc0 * n0x + pc1 * n1x) + pc2 * n2x;
        float ny = (pc0 * n0y + pc1 * n1y) + pc2 * n2y;
        float nz = (pc0 * n0z + pc1 * n1z) + pc2 * n2z;
        float inn = 1.0f / (sqrtf(nx * nx + ny * ny + nz * nz) + EPSF);
        nx *= inn; ny *= inn; nz *= inn;

        float lx = 0.0f - posx, ly = 1.0f - posy, lz = 3.0f - posz;
        float iln = 1.0f / (sqrtf(lx * lx + ly * ly + lz * lz) + EPSF);
        lx *= iln; ly *= iln; lz *= iln;
        float vx = 0.0f - posx, vy = 0.0f - posy, vz = 2.0f - posz;
        float ivn = 1.0f / (sqrtf(vx * vx + vy * vy + vz * vz) + EPSF);
        vx *= ivn; vy *= ivn; vz *= ivn;

        float ndl = nx * lx + ny * ly + nz * lz;
        float ndlr = fmaxf(ndl, 0.0f);
        float rx = 2.0f * ndl * nx - lx;
        float ry = 2.0f * ndl * ny - ly;
        float rz = 2.0f * ndl * nz - lz;
        float sc = fmaxf(rx * vx + ry * vy + rz * vz, 0.0f);
        float spec = 0.2f * 0.6f * powf(sc, 10.0f);
        float shade = 0.5f * 1.0f + 0.3f * 1.0f * ndlr;
        cr = ((142.0f / 255.0f) * shade + spec) * 255.0f;
        cg = ((179.0f / 255.0f) * shade + spec) * 255.0f;
        cb = ((247.0f / 255.0f) * shade + spec) * 255.0f;
    }
    float* img = out + (size_t)b * 3 * HW;
    img[0 * HW + p] = cr;
    img[1 * HW + p] = cg;
    img[2 * HW + p] = cb;
    out[(size_t)NB * 3 * HW + (size_t)b * HW + p] = alpha;
}

extern "C" void kernel_launch(void* const* d_in, const int* in_sizes, int n_in,
                              void* d_out, int out_size, void* d_ws, size_t ws_size,
                              hipStream_t stream) {
    const float* verts = (const float*)d_in[0]; // [NB, NV, 3]
    const int* faces = (const int*)d_in[1];     // [NF, 3]
    char* ws = (char*)d_ws;
    float* vn = (float*)(ws + 0);
    float4* face = (float4*)(ws + OFF_FACE);
    unsigned long long* dbuf = (unsigned long long*)(ws + OFF_DBUF);
    float* out = (float*)d_out;

    hipMemsetAsync(vn, 0, NB * NV * 3 * sizeof(float), stream);
    k_face<<<(NB * NF + 255) / 256, 256, 0, stream>>>(verts, faces, vn, face);
    k_raster<<<NBLK, 128, 0, stream>>>(face, dbuf);
    k_shade<<<(NB * HW) / 64, 64, 0, stream>>>(verts, faces, vn, dbuf, out);
}